// Round 4
// baseline (59.310 us; speedup 1.0000x reference)
//
#include <hip/hip_runtime.h>
#include <math.h>

// B=4, K=256, D=128, H=4, alpha=0.2
// leaky(s) = 0.6*s + 0.4*|s|  (exact for alpha=0.2)
// e_ij = [0.6*(a.Lp_i) cancels in softmax] + 0.6*(a.R_j) + sum_d (0.4 a_d)|Lp_id + R_jd| + bias_ij
// mean_h(P_h @ x) = (mean_h P_h) @ x  ->  accumulate P-bar across heads, single PV.
constexpr int Kc = 256, Dc = 128, Mc = 1024;    // Mc = B*K
constexpr int HMD = 4 * Mc * Dc;                // 524288 floats per ws plane

// ---------------------------------------------------------------------------
// K1 (256 blocks, 256 thr): 64x64-tile fp32 GEMM, 4x4 reg blocking.
//   bid <  128 : Lp[h][m][d] = x@W_src + lin_b          (native layout)
//   bid >= 128 : Rt[(h*4+b)][d][j] = (x@W_dst)^T        (transposed via role swap)
//                + ebase partials eb[(h*4+b)*2+dt][j] = 1.5 * sum_{d in half} 0.4*a_d*R_jd
// ---------------------------------------------------------------------------
__global__ __launch_bounds__(256) void k1(const float* __restrict__ x,
                                          const float* __restrict__ W,
                                          const float* __restrict__ lin_b,
                                          const float* __restrict__ a,
                                          float* __restrict__ Lp,
                                          float* __restrict__ Rt,
                                          float* __restrict__ eb) {
    __shared__ float As[128][64];   // [k][m-role]
    __shared__ float Bs[128][64];   // [k][n-role]
    __shared__ float red[4][16][4];

    const int tid = threadIdx.x;
    const int bid = blockIdx.x;
    const int tx = tid & 15, ty = tid >> 4;
    const bool isL = (bid < 128);

    int h, b, m0, n0, dt;
    if (isL) {
        const int nt = bid & 1, mt = (bid >> 1) & 15;
        h = (bid >> 5) & 3;
        m0 = mt * 64; n0 = nt * 64; b = 0; dt = 0;
        {
            const int m_l = tid & 63, kq = tid >> 6;
            #pragma unroll
            for (int c = 0; c < 8; ++c) {
                const int k0 = kq * 32 + c * 4;
                const float4 v = *(const float4*)&x[(m0 + m_l) * Dc + k0];
                As[k0 + 0][m_l] = v.x; As[k0 + 1][m_l] = v.y;
                As[k0 + 2][m_l] = v.z; As[k0 + 3][m_l] = v.w;
            }
        }
        {
            const int n_l = tid & 63, kq = tid >> 6;
            const float* Wb = W + (h * 2) * Dc * Dc;
            #pragma unroll
            for (int kk = 0; kk < 32; ++kk) {
                const int k = kq * 32 + kk;
                Bs[k][n_l] = Wb[k * Dc + n0 + n_l];
            }
        }
    } else {
        const int r_ = bid - 128;
        const int jt = r_ & 3;
        dt = (r_ >> 2) & 1;
        b  = (r_ >> 3) & 3;
        h  = (r_ >> 5) & 3;
        m0 = dt * 64;          // m-role = d
        n0 = jt * 64;          // n-role = j
        {
            const int d_l = tid & 63, kq = tid >> 6;
            const float* Wb = W + ((h * 2 + 1) * Dc) * Dc;
            #pragma unroll
            for (int kk = 0; kk < 32; ++kk) {
                const int k = kq * 32 + kk;
                As[k][d_l] = Wb[k * Dc + m0 + d_l];
            }
        }
        {
            const int j_l = tid & 63, kq = tid >> 6;
            #pragma unroll
            for (int c = 0; c < 8; ++c) {
                const int k0 = kq * 32 + c * 4;
                const float4 v = *(const float4*)&x[(b * Kc + n0 + j_l) * Dc + k0];
                Bs[k0 + 0][j_l] = v.x; Bs[k0 + 1][j_l] = v.y;
                Bs[k0 + 2][j_l] = v.z; Bs[k0 + 3][j_l] = v.w;
            }
        }
    }
    __syncthreads();

    float acc[4][4];
    #pragma unroll
    for (int r = 0; r < 4; ++r)
        #pragma unroll
        for (int c = 0; c < 4; ++c) acc[r][c] = 0.f;

    #pragma unroll 16
    for (int k = 0; k < 128; ++k) {
        const float4 xa = *(const float4*)&As[k][ty * 4];
        const float4 wb = *(const float4*)&Bs[k][tx * 4];
        acc[0][0] = fmaf(xa.x, wb.x, acc[0][0]);
        acc[0][1] = fmaf(xa.x, wb.y, acc[0][1]);
        acc[0][2] = fmaf(xa.x, wb.z, acc[0][2]);
        acc[0][3] = fmaf(xa.x, wb.w, acc[0][3]);
        acc[1][0] = fmaf(xa.y, wb.x, acc[1][0]);
        acc[1][1] = fmaf(xa.y, wb.y, acc[1][1]);
        acc[1][2] = fmaf(xa.y, wb.z, acc[1][2]);
        acc[1][3] = fmaf(xa.y, wb.w, acc[1][3]);
        acc[2][0] = fmaf(xa.z, wb.x, acc[2][0]);
        acc[2][1] = fmaf(xa.z, wb.y, acc[2][1]);
        acc[2][2] = fmaf(xa.z, wb.z, acc[2][2]);
        acc[2][3] = fmaf(xa.z, wb.w, acc[2][3]);
        acc[3][0] = fmaf(xa.w, wb.x, acc[3][0]);
        acc[3][1] = fmaf(xa.w, wb.y, acc[3][1]);
        acc[3][2] = fmaf(xa.w, wb.z, acc[3][2]);
        acc[3][3] = fmaf(xa.w, wb.w, acc[3][3]);
    }

    if (isL) {
        const float4 lv = *(const float4*)&lin_b[h * Dc + n0 + tx * 4];
        float* dst = Lp + h * (Mc * Dc);
        #pragma unroll
        for (int r = 0; r < 4; ++r) {
            float4 o;
            o.x = acc[r][0] + lv.x; o.y = acc[r][1] + lv.y;
            o.z = acc[r][2] + lv.z; o.w = acc[r][3] + lv.w;
            *(float4*)&dst[(m0 + ty * 4 + r) * Dc + n0 + tx * 4] = o;
        }
    } else {
        float* dst = Rt + ((h * 4 + b) * Dc + m0) * Kc + n0;
        #pragma unroll
        for (int r = 0; r < 4; ++r) {
            float4 o;
            o.x = acc[r][0]; o.y = acc[r][1]; o.z = acc[r][2]; o.w = acc[r][3];
            *(float4*)&dst[(ty * 4 + r) * Kc + tx * 4] = o;
        }
        const float4 av = *(const float4*)&a[h * Dc + m0 + ty * 4];
        float p0 = 0.4f * (av.x * acc[0][0] + av.y * acc[1][0] + av.z * acc[2][0] + av.w * acc[3][0]);
        float p1 = 0.4f * (av.x * acc[0][1] + av.y * acc[1][1] + av.z * acc[2][1] + av.w * acc[3][1]);
        float p2 = 0.4f * (av.x * acc[0][2] + av.y * acc[1][2] + av.z * acc[2][2] + av.w * acc[3][2]);
        float p3 = 0.4f * (av.x * acc[0][3] + av.y * acc[1][3] + av.z * acc[2][3] + av.w * acc[3][3]);
        p0 += __shfl_xor(p0, 16, 64); p0 += __shfl_xor(p0, 32, 64);
        p1 += __shfl_xor(p1, 16, 64); p1 += __shfl_xor(p1, 32, 64);
        p2 += __shfl_xor(p2, 16, 64); p2 += __shfl_xor(p2, 32, 64);
        p3 += __shfl_xor(p3, 16, 64); p3 += __shfl_xor(p3, 32, 64);
        if (((tid >> 4) & 3) == 0) {
            const int w = tid >> 6;
            red[w][tx][0] = p0; red[w][tx][1] = p1;
            red[w][tx][2] = p2; red[w][tx][3] = p3;
        }
        __syncthreads();
        if (tid < 64) {
            const int txl = tid >> 2, c = tid & 3;
            const float v = red[0][txl][c] + red[1][txl][c] + red[2][txl][c] + red[3][txl][c];
            eb[((h * 4 + b) * 2 + dt) * Kc + n0 + tid] = 1.5f * v;
        }
    }
}

// ---------------------------------------------------------------------------
// K2 (256 blocks = b x 64 i-tiles of 4 rows, 256 thr): all 4 heads per block.
//   per h : e-phase (thread (dq,j4) owns acc[4i][4j] over 32-d slice, Rt from
//           global/L2) -> padded-LDS dq-reduce -> 1-row-per-wave shuffle
//           softmax -> accumulate P-bar (0.25/s) into pl[i][j].
//   then  : single PV with P-bar, x from global/L2, jq-reduce, write final out.
// ---------------------------------------------------------------------------
#define EROW(ACC, LPV)                                            \
    ACC.x = fmaf(aad, __builtin_fabsf((LPV) + rr.x), ACC.x);      \
    ACC.y = fmaf(aad, __builtin_fabsf((LPV) + rr.y), ACC.y);      \
    ACC.z = fmaf(aad, __builtin_fabsf((LPV) + rr.z), ACC.z);      \
    ACC.w = fmaf(aad, __builtin_fabsf((LPV) + rr.w), ACC.w);

__global__ __launch_bounds__(256) void k2(const float* __restrict__ x,
                                          const float* __restrict__ a,
                                          const float* __restrict__ bias,
                                          const float* __restrict__ Lp,
                                          const float* __restrict__ Rt,
                                          const float* __restrict__ eb,
                                          float* __restrict__ out) {
    __shared__ float red[256 * 20];     // 20 KB reduce scratch (stride 20: pad vs banks)
    __shared__ float lpT[4 * Dc * 4];   // [h][d][i] 8 KB
    __shared__ float aaT[4 * Dc];       // 0.4*a, 2 KB
    __shared__ float pl[4 * Kc];        // P-bar accumulator [i][j], 4 KB

    const int tid = threadIdx.x;
    const int bid0 = blockIdx.x;
    const int bid = (bid0 & 7) * 32 + (bid0 >> 3);   // XCD swizzle (256%8==0): each XCD stays on one b
    const int it = bid & 63, b = bid >> 6;
    const int i0 = it * 4;

    // ---- stage lpT[h][d][i] (global reads coalesced along d) + aaT + zero pl ----
    {
        const int d_s = tid & 127;
        const int hh = tid >> 7;          // 0..1
        #pragma unroll
        for (int t = 0; t < 2; ++t) {
            const int h = hh * 2 + t;
            const float* lrow = Lp + (h * Mc + b * Kc + i0) * Dc + d_s;
            float* dst = lpT + (h * Dc + d_s) * 4;
            dst[0] = lrow[0 * Dc];
            dst[1] = lrow[1 * Dc];
            dst[2] = lrow[2 * Dc];
            dst[3] = lrow[3 * Dc];
        }
    }
    if (tid < 128) {
        #pragma unroll
        for (int h = 0; h < 4; ++h)
            aaT[h * Dc + tid] = 0.4f * a[h * Dc + tid];
    }
    ((float4*)pl)[tid] = make_float4(0.f, 0.f, 0.f, 0.f);
    __syncthreads();

    const int dq = tid >> 6, j4 = tid & 63;   // e-phase decomposition
    const int w  = dq,      l  = j4;          // softmax: wave w owns row i=w

    #pragma unroll 1
    for (int h = 0; h < 4; ++h) {
        const int hb = h * 4 + b;
        float4 acc0 = make_float4(0.f, 0.f, 0.f, 0.f);
        float4 acc1 = make_float4(0.f, 0.f, 0.f, 0.f);
        float4 acc2 = make_float4(0.f, 0.f, 0.f, 0.f);
        float4 acc3 = make_float4(0.f, 0.f, 0.f, 0.f);
        const float* rb = Rt + (hb * Dc + dq * 32) * Kc + j4 * 4;
        const float* lt = lpT + (h * Dc + dq * 32) * 4;
        const float* at = aaT + h * Dc + dq * 32;
        #pragma unroll 8
        for (int dd = 0; dd < 32; ++dd) {
            const float4 rr = *(const float4*)(rb + dd * Kc);   // global, L2-hot
            const float aad = at[dd];                           // LDS broadcast
            const float4 l0 = *(const float4*)(lt + dd * 4);    // LDS broadcast b128
            EROW(acc0, l0.x); EROW(acc1, l0.y);
            EROW(acc2, l0.z); EROW(acc3, l0.w);
        }
        {
            float* myred = red + (dq * 64 + j4) * 20;
            *(float4*)&myred[0]  = acc0;
            *(float4*)&myred[4]  = acc1;
            *(float4*)&myred[8]  = acc2;
            *(float4*)&myred[12] = acc3;
        }
        __syncthreads();

        // ---- softmax row i0+w across this wave's 64 lanes ----
        {
            float4 e0 = make_float4(0.f, 0.f, 0.f, 0.f);
            #pragma unroll
            for (int q = 0; q < 4; ++q) {
                const float4 v = *(const float4*)&red[(q * 64 + l) * 20 + w * 4];
                e0.x += v.x; e0.y += v.y; e0.z += v.z; e0.w += v.w;
            }
            const float4 eb0 = *(const float4*)&eb[(hb * 2 + 0) * Kc + l * 4];
            const float4 eb1 = *(const float4*)&eb[(hb * 2 + 1) * Kc + l * 4];
            const float4 bv  = *(const float4*)&bias[(h * Kc + i0 + w) * Kc + l * 4];
            e0.x += eb0.x + eb1.x + bv.x;
            e0.y += eb0.y + eb1.y + bv.y;
            e0.z += eb0.z + eb1.z + bv.z;
            e0.w += eb0.w + eb1.w + bv.w;

            float m = fmaxf(fmaxf(e0.x, e0.y), fmaxf(e0.z, e0.w));
            #pragma unroll
            for (int off = 1; off < 64; off <<= 1) m = fmaxf(m, __shfl_xor(m, off, 64));
            const float p0 = __expf(e0.x - m), p1 = __expf(e0.y - m);
            const float p2 = __expf(e0.z - m), p3 = __expf(e0.w - m);
            float s = p0 + p1 + p2 + p3;
            #pragma unroll
            for (int off = 1; off < 64; off <<= 1) s += __shfl_xor(s, off, 64);
            const float sc = 0.25f / s;        // fold mean over H
            float4 cur = *(float4*)&pl[w * Kc + l * 4];
            cur.x = fmaf(p0, sc, cur.x);
            cur.y = fmaf(p1, sc, cur.y);
            cur.z = fmaf(p2, sc, cur.z);
            cur.w = fmaf(p3, sc, cur.w);
            *(float4*)&pl[w * Kc + l * 4] = cur;
        }
        __syncthreads();
    }

    // ---- single PV with P-bar: o[i][d] = sum_j pl[i][j] * x[b][j][d] ----
    const int jq = tid >> 5, dd4 = tid & 31;
    float4 o0 = make_float4(0.f, 0.f, 0.f, 0.f);
    float4 o1 = make_float4(0.f, 0.f, 0.f, 0.f);
    float4 o2 = make_float4(0.f, 0.f, 0.f, 0.f);
    float4 o3 = make_float4(0.f, 0.f, 0.f, 0.f);
    {
        const float* xb = x + (b * Kc) * Dc + dd4 * 4;
        #pragma unroll 4
        for (int jj = 0; jj < 32; ++jj) {
            const int j = jj * 8 + jq;
            const float4 xv = *(const float4*)(xb + j * Dc);   // global, L2-hot
            const float pv0 = pl[0 * Kc + j];                  // LDS broadcast
            const float pv1 = pl[1 * Kc + j];
            const float pv2 = pl[2 * Kc + j];
            const float pv3 = pl[3 * Kc + j];
            o0.x = fmaf(pv0, xv.x, o0.x); o0.y = fmaf(pv0, xv.y, o0.y);
            o0.z = fmaf(pv0, xv.z, o0.z); o0.w = fmaf(pv0, xv.w, o0.w);
            o1.x = fmaf(pv1, xv.x, o1.x); o1.y = fmaf(pv1, xv.y, o1.y);
            o1.z = fmaf(pv1, xv.z, o1.z); o1.w = fmaf(pv1, xv.w, o1.w);
            o2.x = fmaf(pv2, xv.x, o2.x); o2.y = fmaf(pv2, xv.y, o2.y);
            o2.z = fmaf(pv2, xv.z, o2.z); o2.w = fmaf(pv2, xv.w, o2.w);
            o3.x = fmaf(pv3, xv.x, o3.x); o3.y = fmaf(pv3, xv.y, o3.y);
            o3.z = fmaf(pv3, xv.z, o3.z); o3.w = fmaf(pv3, xv.w, o3.w);
        }
    }
    {
        float* myred = red + (jq * 32 + dd4) * 20;
        *(float4*)&myred[0]  = o0;
        *(float4*)&myred[4]  = o1;
        *(float4*)&myred[8]  = o2;
        *(float4*)&myred[12] = o3;
    }
    __syncthreads();
    if (tid < 128) {
        const int i_f = tid >> 5, dd_f = tid & 31;
        float4 s = make_float4(0.f, 0.f, 0.f, 0.f);
        #pragma unroll
        for (int q = 0; q < 8; ++q) {
            const float4 v = *(const float4*)&red[(q * 32 + dd_f) * 20 + i_f * 4];
            s.x += v.x; s.y += v.y; s.z += v.z; s.w += v.w;
        }
        *(float4*)&out[(b * Kc + i0 + i_f) * Dc + dd_f * 4] = s;
    }
}

extern "C" void kernel_launch(void* const* d_in, const int* in_sizes, int n_in,
                              void* d_out, int out_size, void* d_ws, size_t ws_size,
                              hipStream_t stream) {
    const float* x     = (const float*)d_in[0];
    const float* W     = (const float*)d_in[1];
    const float* lin_b = (const float*)d_in[2];
    const float* a     = (const float*)d_in[3];
    const float* bias  = (const float*)d_in[4];
    float* out = (float*)d_out;

    float* Lp = (float*)d_ws;          // [H][M][D]
    float* Rt = Lp + HMD;              // [(H*B)][D][K]
    float* eb = Rt + HMD;              // [(H*B)][2][K] = 8192 floats (in ws: k2 writes out!)

    k1<<<256, 256, 0, stream>>>(x, W, lin_b, a, Lp, Rt, eb);
    k2<<<256, 256, 0, stream>>>(x, a, bias, Lp, Rt, eb, out);
}

// Round 5
// 32.781 us; speedup vs baseline: 1.8093x; 1.8093x over previous
//
#include <hip/hip_runtime.h>
#include <math.h>

// B=4, K=256, D=128, H=4, alpha=0.2
// leaky(s) = 0.6*s + 0.4*|s|  (exact for alpha=0.2)
// e_ij = [0.6*(a.Lp_i) cancels in softmax] + 0.6*(a.R_j) + sum_d (0.4 a_d)|Lp_id + R_jd| + bias_ij
// mean_h(P_h @ x) = (mean_h P_h) @ x  ->  k2 writes 0.25*P per head; k3 sums + single PV.
constexpr int Kc = 256, Dc = 128, Mc = 1024;    // Mc = B*K
constexpr int HMD = 4 * Mc * Dc;                // 524288 floats per ws plane

// ---------------------------------------------------------------------------
// K1 (256 blocks, 256 thr): 64x64-tile fp32 GEMM, 4x4 reg blocking.
//   bid <  128 : Lp[h][m][d] = x@W_src + lin_b          (native layout)
//   bid >= 128 : Rt[(h*4+b)][d][j] = (x@W_dst)^T        (transposed via role swap)
//                + ebase partials eb[(h*4+b)*2+dt][j] = 1.5 * sum_{d in half} 0.4*a_d*R_jd
// ---------------------------------------------------------------------------
__global__ __launch_bounds__(256) void k1(const float* __restrict__ x,
                                          const float* __restrict__ W,
                                          const float* __restrict__ lin_b,
                                          const float* __restrict__ a,
                                          float* __restrict__ Lp,
                                          float* __restrict__ Rt,
                                          float* __restrict__ eb) {
    __shared__ float As[128][64];   // [k][m-role]
    __shared__ float Bs[128][64];   // [k][n-role]
    __shared__ float red[4][16][4];

    const int tid = threadIdx.x;
    const int bid = blockIdx.x;
    const int tx = tid & 15, ty = tid >> 4;
    const bool isL = (bid < 128);

    int h, b, m0, n0, dt;
    if (isL) {
        const int nt = bid & 1, mt = (bid >> 1) & 15;
        h = (bid >> 5) & 3;
        m0 = mt * 64; n0 = nt * 64; b = 0; dt = 0;
        {
            const int m_l = tid & 63, kq = tid >> 6;
            #pragma unroll
            for (int c = 0; c < 8; ++c) {
                const int k0 = kq * 32 + c * 4;
                const float4 v = *(const float4*)&x[(m0 + m_l) * Dc + k0];
                As[k0 + 0][m_l] = v.x; As[k0 + 1][m_l] = v.y;
                As[k0 + 2][m_l] = v.z; As[k0 + 3][m_l] = v.w;
            }
        }
        {
            const int n_l = tid & 63, kq = tid >> 6;
            const float* Wb = W + (h * 2) * Dc * Dc;
            #pragma unroll
            for (int kk = 0; kk < 32; ++kk) {
                const int k = kq * 32 + kk;
                Bs[k][n_l] = Wb[k * Dc + n0 + n_l];
            }
        }
    } else {
        const int r_ = bid - 128;
        const int jt = r_ & 3;
        dt = (r_ >> 2) & 1;
        b  = (r_ >> 3) & 3;
        h  = (r_ >> 5) & 3;
        m0 = dt * 64;          // m-role = d
        n0 = jt * 64;          // n-role = j
        {
            const int d_l = tid & 63, kq = tid >> 6;
            const float* Wb = W + ((h * 2 + 1) * Dc) * Dc;
            #pragma unroll
            for (int kk = 0; kk < 32; ++kk) {
                const int k = kq * 32 + kk;
                As[k][d_l] = Wb[k * Dc + m0 + d_l];
            }
        }
        {
            const int j_l = tid & 63, kq = tid >> 6;
            #pragma unroll
            for (int c = 0; c < 8; ++c) {
                const int k0 = kq * 32 + c * 4;
                const float4 v = *(const float4*)&x[(b * Kc + n0 + j_l) * Dc + k0];
                Bs[k0 + 0][j_l] = v.x; Bs[k0 + 1][j_l] = v.y;
                Bs[k0 + 2][j_l] = v.z; Bs[k0 + 3][j_l] = v.w;
            }
        }
    }
    __syncthreads();

    float acc[4][4];
    #pragma unroll
    for (int r = 0; r < 4; ++r)
        #pragma unroll
        for (int c = 0; c < 4; ++c) acc[r][c] = 0.f;

    #pragma unroll 16
    for (int k = 0; k < 128; ++k) {
        const float4 xa = *(const float4*)&As[k][ty * 4];
        const float4 wb = *(const float4*)&Bs[k][tx * 4];
        acc[0][0] = fmaf(xa.x, wb.x, acc[0][0]);
        acc[0][1] = fmaf(xa.x, wb.y, acc[0][1]);
        acc[0][2] = fmaf(xa.x, wb.z, acc[0][2]);
        acc[0][3] = fmaf(xa.x, wb.w, acc[0][3]);
        acc[1][0] = fmaf(xa.y, wb.x, acc[1][0]);
        acc[1][1] = fmaf(xa.y, wb.y, acc[1][1]);
        acc[1][2] = fmaf(xa.y, wb.z, acc[1][2]);
        acc[1][3] = fmaf(xa.y, wb.w, acc[1][3]);
        acc[2][0] = fmaf(xa.z, wb.x, acc[2][0]);
        acc[2][1] = fmaf(xa.z, wb.y, acc[2][1]);
        acc[2][2] = fmaf(xa.z, wb.z, acc[2][2]);
        acc[2][3] = fmaf(xa.z, wb.w, acc[2][3]);
        acc[3][0] = fmaf(xa.w, wb.x, acc[3][0]);
        acc[3][1] = fmaf(xa.w, wb.y, acc[3][1]);
        acc[3][2] = fmaf(xa.w, wb.z, acc[3][2]);
        acc[3][3] = fmaf(xa.w, wb.w, acc[3][3]);
    }

    if (isL) {
        const float4 lv = *(const float4*)&lin_b[h * Dc + n0 + tx * 4];
        float* dst = Lp + h * (Mc * Dc);
        #pragma unroll
        for (int r = 0; r < 4; ++r) {
            float4 o;
            o.x = acc[r][0] + lv.x; o.y = acc[r][1] + lv.y;
            o.z = acc[r][2] + lv.z; o.w = acc[r][3] + lv.w;
            *(float4*)&dst[(m0 + ty * 4 + r) * Dc + n0 + tx * 4] = o;
        }
    } else {
        float* dst = Rt + ((h * 4 + b) * Dc + m0) * Kc + n0;
        #pragma unroll
        for (int r = 0; r < 4; ++r) {
            float4 o;
            o.x = acc[r][0]; o.y = acc[r][1]; o.z = acc[r][2]; o.w = acc[r][3];
            *(float4*)&dst[(ty * 4 + r) * Kc + tx * 4] = o;
        }
        const float4 av = *(const float4*)&a[h * Dc + m0 + ty * 4];
        float p0 = 0.4f * (av.x * acc[0][0] + av.y * acc[1][0] + av.z * acc[2][0] + av.w * acc[3][0]);
        float p1 = 0.4f * (av.x * acc[0][1] + av.y * acc[1][1] + av.z * acc[2][1] + av.w * acc[3][1]);
        float p2 = 0.4f * (av.x * acc[0][2] + av.y * acc[1][2] + av.z * acc[2][2] + av.w * acc[3][2]);
        float p3 = 0.4f * (av.x * acc[0][3] + av.y * acc[1][3] + av.z * acc[2][3] + av.w * acc[3][3]);
        p0 += __shfl_xor(p0, 16, 64); p0 += __shfl_xor(p0, 32, 64);
        p1 += __shfl_xor(p1, 16, 64); p1 += __shfl_xor(p1, 32, 64);
        p2 += __shfl_xor(p2, 16, 64); p2 += __shfl_xor(p2, 32, 64);
        p3 += __shfl_xor(p3, 16, 64); p3 += __shfl_xor(p3, 32, 64);
        if (((tid >> 4) & 3) == 0) {
            const int w = tid >> 6;
            red[w][tx][0] = p0; red[w][tx][1] = p1;
            red[w][tx][2] = p2; red[w][tx][3] = p3;
        }
        __syncthreads();
        if (tid < 64) {
            const int txl = tid >> 2, c = tid & 3;
            const float v = red[0][txl][c] + red[1][txl][c] + red[2][txl][c] + red[3][txl][c];
            eb[((h * 4 + b) * 2 + dt) * Kc + n0 + tid] = 1.5f * v;
        }
    }
}

// ---------------------------------------------------------------------------
// K2 (1024 blocks = (hb, 64 i-tiles of 4 rows), 256 thr, XCD-pinned):
//   e-phase: thread (dq=tid>>6, j4=tid&63) owns acc[4i][4j] over a 32-d slice;
//   Rt read from global (L2-pinned: blocks with same hb share an XCD).
//   Padded-LDS dq-reduce -> wave-per-row shuffle softmax -> write 0.25*P to Pws.
// ---------------------------------------------------------------------------
#define EROW(ACC, LPV)                                            \
    ACC.x = fmaf(aad, __builtin_fabsf((LPV) + rr.x), ACC.x);      \
    ACC.y = fmaf(aad, __builtin_fabsf((LPV) + rr.y), ACC.y);      \
    ACC.z = fmaf(aad, __builtin_fabsf((LPV) + rr.z), ACC.z);      \
    ACC.w = fmaf(aad, __builtin_fabsf((LPV) + rr.w), ACC.w);

__global__ __launch_bounds__(256) void k2(const float* __restrict__ a,
                                          const float* __restrict__ bias,
                                          const float* __restrict__ Lp,
                                          const float* __restrict__ Rt,
                                          const float* __restrict__ eb,
                                          float* __restrict__ Pws) {
    __shared__ float red[256 * 20];   // 20 KB dq-reduce scratch
    __shared__ float lpT[Dc * 4];     // [d][i] 2 KB
    __shared__ float aa[Dc];          // 0.4*a[h]

    const int tid = threadIdx.x;
    const int L = blockIdx.x;
    // XCD-pin: launch-id L%8 selects XCD (dispatch heuristic); hb = (L&7)*2 | parity.
    const int xcd = L & 7, q = L >> 3;
    const int hb = (xcd << 1) | (q & 1);   // 0..15, constant per XCD (2 planes each)
    const int it = q >> 1;                 // 0..63
    const int h = hb >> 2, b = hb & 3;
    const int i0 = it * 4;

    // stage lpT[d][i] (coalesced along d) + aa
    {
        const int d_s = tid & 127, half = tid >> 7;
        const float* lrow = Lp + (h * Mc + b * Kc + i0 + half * 2) * Dc + d_s;
        lpT[d_s * 4 + half * 2 + 0] = lrow[0];
        lpT[d_s * 4 + half * 2 + 1] = lrow[Dc];
    }
    if (tid < 128) aa[tid] = 0.4f * a[h * Dc + tid];
    __syncthreads();

    const int dq = tid >> 6, j4 = tid & 63;
    float4 acc0 = make_float4(0.f, 0.f, 0.f, 0.f);
    float4 acc1 = make_float4(0.f, 0.f, 0.f, 0.f);
    float4 acc2 = make_float4(0.f, 0.f, 0.f, 0.f);
    float4 acc3 = make_float4(0.f, 0.f, 0.f, 0.f);
    {
        const float* rb = Rt + (hb * Dc + dq * 32) * Kc + j4 * 4;
        const float* lt = lpT + dq * 32 * 4;
        const float* at = aa + dq * 32;
        #pragma unroll 8
        for (int dd = 0; dd < 32; ++dd) {
            const float4 rr = *(const float4*)(rb + dd * Kc);   // global, L2-hot
            const float aad = at[dd];                           // LDS broadcast
            const float4 l0 = *(const float4*)(lt + dd * 4);    // LDS broadcast b128
            EROW(acc0, l0.x); EROW(acc1, l0.y);
            EROW(acc2, l0.z); EROW(acc3, l0.w);
        }
    }
    {
        float* myred = red + tid * 20;
        *(float4*)&myred[0]  = acc0;
        *(float4*)&myred[4]  = acc1;
        *(float4*)&myred[8]  = acc2;
        *(float4*)&myred[12] = acc3;
    }
    __syncthreads();

    // softmax: wave w owns row i0+w; lane l = j-quad
    {
        const int w = tid >> 6, l = tid & 63;
        float4 e0 = make_float4(0.f, 0.f, 0.f, 0.f);
        #pragma unroll
        for (int q4 = 0; q4 < 4; ++q4) {
            const float4 v = *(const float4*)&red[(q4 * 64 + l) * 20 + w * 4];
            e0.x += v.x; e0.y += v.y; e0.z += v.z; e0.w += v.w;
        }
        const float4 eb0 = *(const float4*)&eb[(hb * 2 + 0) * Kc + l * 4];
        const float4 eb1 = *(const float4*)&eb[(hb * 2 + 1) * Kc + l * 4];
        const float4 bv  = *(const float4*)&bias[(h * Kc + i0 + w) * Kc + l * 4];
        e0.x += eb0.x + eb1.x + bv.x;
        e0.y += eb0.y + eb1.y + bv.y;
        e0.z += eb0.z + eb1.z + bv.z;
        e0.w += eb0.w + eb1.w + bv.w;

        float m = fmaxf(fmaxf(e0.x, e0.y), fmaxf(e0.z, e0.w));
        #pragma unroll
        for (int off = 1; off < 64; off <<= 1) m = fmaxf(m, __shfl_xor(m, off, 64));
        const float p0 = __expf(e0.x - m), p1 = __expf(e0.y - m);
        const float p2 = __expf(e0.z - m), p3 = __expf(e0.w - m);
        float s = p0 + p1 + p2 + p3;
        #pragma unroll
        for (int off = 1; off < 64; off <<= 1) s += __shfl_xor(s, off, 64);
        const float sc = 0.25f / s;     // fold mean over H
        *(float4*)&Pws[(hb * Kc + i0 + w) * Kc + l * 4] =
            make_float4(p0 * sc, p1 * sc, p2 * sc, p3 * sc);
    }
}

// ---------------------------------------------------------------------------
// K3 (512 blocks = (b, 128 i-tiles of 2 rows), 256 thr): P-bar = sum_h Pws,
// then single PV: out[i][d] = sum_j Pbar[i][j] * x[b][j][d].
// ---------------------------------------------------------------------------
__global__ __launch_bounds__(256) void k3(const float* __restrict__ x,
                                          const float* __restrict__ Pws,
                                          float* __restrict__ out) {
    __shared__ float pbar[2 * Kc];    // 2 KB
    __shared__ float red[256 * 12];   // 12 KB jq-reduce scratch

    const int tid = threadIdx.x;
    const int bid = blockIdx.x;
    const int b = bid >> 7, it = bid & 127;
    const int i0 = it * 2;

    if (tid < 128) {
        const int r = tid >> 6, c = tid & 63;
        float4 s = make_float4(0.f, 0.f, 0.f, 0.f);
        #pragma unroll
        for (int h = 0; h < 4; ++h) {
            const float4 v = *(const float4*)&Pws[((h * 4 + b) * Kc + i0 + r) * Kc + c * 4];
            s.x += v.x; s.y += v.y; s.z += v.z; s.w += v.w;
        }
        *(float4*)&pbar[r * Kc + c * 4] = s;
    }
    __syncthreads();

    const int jq = tid >> 5, dd4 = tid & 31;
    float4 o0 = make_float4(0.f, 0.f, 0.f, 0.f);
    float4 o1 = make_float4(0.f, 0.f, 0.f, 0.f);
    {
        const float* xb = x + (b * Kc) * Dc + dd4 * 4;
        #pragma unroll 4
        for (int jj = 0; jj < 32; ++jj) {
            const int j = jj * 8 + jq;
            const float4 xv = *(const float4*)(xb + j * Dc);   // global, L2-hot
            const float pv0 = pbar[j];                          // LDS broadcast
            const float pv1 = pbar[Kc + j];
            o0.x = fmaf(pv0, xv.x, o0.x); o0.y = fmaf(pv0, xv.y, o0.y);
            o0.z = fmaf(pv0, xv.z, o0.z); o0.w = fmaf(pv0, xv.w, o0.w);
            o1.x = fmaf(pv1, xv.x, o1.x); o1.y = fmaf(pv1, xv.y, o1.y);
            o1.z = fmaf(pv1, xv.z, o1.z); o1.w = fmaf(pv1, xv.w, o1.w);
        }
    }
    {
        float* myred = red + (jq * 32 + dd4) * 12;
        *(float4*)&myred[0] = o0;
        *(float4*)&myred[4] = o1;
    }
    __syncthreads();
    if (tid < 64) {
        const int i_f = tid >> 5, dd_f = tid & 31;
        float4 s = make_float4(0.f, 0.f, 0.f, 0.f);
        #pragma unroll
        for (int q = 0; q < 8; ++q) {
            const float4 v = *(const float4*)&red[(q * 32 + dd_f) * 12 + i_f * 4];
            s.x += v.x; s.y += v.y; s.z += v.z; s.w += v.w;
        }
        *(float4*)&out[(b * Kc + i0 + i_f) * Dc + dd_f * 4] = s;
    }
}

extern "C" void kernel_launch(void* const* d_in, const int* in_sizes, int n_in,
                              void* d_out, int out_size, void* d_ws, size_t ws_size,
                              hipStream_t stream) {
    const float* x     = (const float*)d_in[0];
    const float* W     = (const float*)d_in[1];
    const float* lin_b = (const float*)d_in[2];
    const float* a     = (const float*)d_in[3];
    const float* bias  = (const float*)d_in[4];
    float* out = (float*)d_out;

    float* Lp  = (float*)d_ws;         // [H][M][D]
    float* Rt  = Lp + HMD;             // [(H*B)][D][K]
    float* eb  = Rt + HMD;             // [(H*B)][2][K] = 8192 floats
    float* Pws = eb + 8192;            // [(H*B)][K][K] = 1048576 floats (4 MB)

    k1<<<256, 256, 0, stream>>>(x, W, lin_b, a, Lp, Rt, eb);
    k2<<<1024, 256, 0, stream>>>(a, bias, Lp, Rt, eb, Pws);
    k3<<<512, 256, 0, stream>>>(x, Pws, out);
}

// Round 6
// 30.121 us; speedup vs baseline: 1.9691x; 1.0883x over previous
//
#include <hip/hip_runtime.h>
#include <math.h>

// B=4, K=256, D=128, H=4, alpha=0.2
// leaky(s) = 0.6*s + 0.4*|s|  (exact for alpha=0.2)
// e_ij = [0.6*(a.Lp_i) cancels in softmax] + 0.6*(a.R_j) + sum_d (0.4 a_d)|Lp_id + R_jd| + bias_ij
// mean_h(P_h @ x) = (mean_h P_h) @ x  ->  k2 writes 0.25*P per head (bf16); k3 sums + single PV.
// Rt and Pws are bf16 intermediates to halve the ws byte path (L2/HBM).
constexpr int Kc = 256, Dc = 128, Mc = 1024;    // Mc = B*K
constexpr int HMD = 4 * Mc * Dc;                // 524288 elements per plane

__device__ inline unsigned int f2bf(float f) {      // fp32 -> bf16 bits (RNE)
    unsigned int u = __float_as_uint(f);
    return (u + 0x7FFFu + ((u >> 16) & 1u)) >> 16;
}
__device__ inline float bf2f_lo(unsigned int u) { return __uint_as_float(u << 16); }
__device__ inline float bf2f_hi(unsigned int u) { return __uint_as_float(u & 0xFFFF0000u); }

// ---------------------------------------------------------------------------
// K1 (256 blocks, 256 thr): 64x64-tile fp32 GEMM, 4x4 reg blocking.
//   bid <  128 : Lp[h][m][d] = x@W_src + lin_b          (fp32, native layout)
//   bid >= 128 : Rt[(h*4+b)][d][j] = (x@W_dst)^T        (bf16, transposed)
//                + eb[(h*4+b)*2+dt][j] = 1.5 * sum_{d in half} 0.4*a_d*R_jd (fp32)
// ---------------------------------------------------------------------------
__global__ __launch_bounds__(256) void k1(const float* __restrict__ x,
                                          const float* __restrict__ W,
                                          const float* __restrict__ lin_b,
                                          const float* __restrict__ a,
                                          float* __restrict__ Lp,
                                          unsigned short* __restrict__ Rt,
                                          float* __restrict__ eb) {
    __shared__ float As[128][64];   // [k][m-role]
    __shared__ float Bs[128][64];   // [k][n-role]
    __shared__ float red[4][16][4];

    const int tid = threadIdx.x;
    const int bid = blockIdx.x;
    const int tx = tid & 15, ty = tid >> 4;
    const bool isL = (bid < 128);

    int h, b, m0, n0, dt;
    if (isL) {
        const int nt = bid & 1, mt = (bid >> 1) & 15;
        h = (bid >> 5) & 3;
        m0 = mt * 64; n0 = nt * 64; b = 0; dt = 0;
        {
            const int m_l = tid & 63, kq = tid >> 6;
            #pragma unroll
            for (int c = 0; c < 8; ++c) {
                const int k0 = kq * 32 + c * 4;
                const float4 v = *(const float4*)&x[(m0 + m_l) * Dc + k0];
                As[k0 + 0][m_l] = v.x; As[k0 + 1][m_l] = v.y;
                As[k0 + 2][m_l] = v.z; As[k0 + 3][m_l] = v.w;
            }
        }
        {
            const int n_l = tid & 63, kq = tid >> 6;
            const float* Wb = W + (h * 2) * Dc * Dc;
            #pragma unroll
            for (int kk = 0; kk < 32; ++kk) {
                const int k = kq * 32 + kk;
                Bs[k][n_l] = Wb[k * Dc + n0 + n_l];
            }
        }
    } else {
        const int r_ = bid - 128;
        const int jt = r_ & 3;
        dt = (r_ >> 2) & 1;
        b  = (r_ >> 3) & 3;
        h  = (r_ >> 5) & 3;
        m0 = dt * 64;          // m-role = d
        n0 = jt * 64;          // n-role = j
        {
            const int d_l = tid & 63, kq = tid >> 6;
            const float* Wb = W + ((h * 2 + 1) * Dc) * Dc;
            #pragma unroll
            for (int kk = 0; kk < 32; ++kk) {
                const int k = kq * 32 + kk;
                As[k][d_l] = Wb[k * Dc + m0 + d_l];
            }
        }
        {
            const int j_l = tid & 63, kq = tid >> 6;
            #pragma unroll
            for (int c = 0; c < 8; ++c) {
                const int k0 = kq * 32 + c * 4;
                const float4 v = *(const float4*)&x[(b * Kc + n0 + j_l) * Dc + k0];
                Bs[k0 + 0][j_l] = v.x; Bs[k0 + 1][j_l] = v.y;
                Bs[k0 + 2][j_l] = v.z; Bs[k0 + 3][j_l] = v.w;
            }
        }
    }
    __syncthreads();

    float acc[4][4];
    #pragma unroll
    for (int r = 0; r < 4; ++r)
        #pragma unroll
        for (int c = 0; c < 4; ++c) acc[r][c] = 0.f;

    #pragma unroll 16
    for (int k = 0; k < 128; ++k) {
        const float4 xa = *(const float4*)&As[k][ty * 4];
        const float4 wb = *(const float4*)&Bs[k][tx * 4];
        acc[0][0] = fmaf(xa.x, wb.x, acc[0][0]);
        acc[0][1] = fmaf(xa.x, wb.y, acc[0][1]);
        acc[0][2] = fmaf(xa.x, wb.z, acc[0][2]);
        acc[0][3] = fmaf(xa.x, wb.w, acc[0][3]);
        acc[1][0] = fmaf(xa.y, wb.x, acc[1][0]);
        acc[1][1] = fmaf(xa.y, wb.y, acc[1][1]);
        acc[1][2] = fmaf(xa.y, wb.z, acc[1][2]);
        acc[1][3] = fmaf(xa.y, wb.w, acc[1][3]);
        acc[2][0] = fmaf(xa.z, wb.x, acc[2][0]);
        acc[2][1] = fmaf(xa.z, wb.y, acc[2][1]);
        acc[2][2] = fmaf(xa.z, wb.z, acc[2][2]);
        acc[2][3] = fmaf(xa.z, wb.w, acc[2][3]);
        acc[3][0] = fmaf(xa.w, wb.x, acc[3][0]);
        acc[3][1] = fmaf(xa.w, wb.y, acc[3][1]);
        acc[3][2] = fmaf(xa.w, wb.z, acc[3][2]);
        acc[3][3] = fmaf(xa.w, wb.w, acc[3][3]);
    }

    if (isL) {
        const float4 lv = *(const float4*)&lin_b[h * Dc + n0 + tx * 4];
        float* dst = Lp + h * (Mc * Dc);
        #pragma unroll
        for (int r = 0; r < 4; ++r) {
            float4 o;
            o.x = acc[r][0] + lv.x; o.y = acc[r][1] + lv.y;
            o.z = acc[r][2] + lv.z; o.w = acc[r][3] + lv.w;
            *(float4*)&dst[(m0 + ty * 4 + r) * Dc + n0 + tx * 4] = o;
        }
    } else {
        unsigned short* dst = Rt + ((h * 4 + b) * Dc + m0) * Kc + n0;
        #pragma unroll
        for (int r = 0; r < 4; ++r) {
            uint2 pk;
            pk.x = f2bf(acc[r][0]) | (f2bf(acc[r][1]) << 16);
            pk.y = f2bf(acc[r][2]) | (f2bf(acc[r][3]) << 16);
            *(uint2*)&dst[(ty * 4 + r) * Kc + tx * 4] = pk;
        }
        const float4 av = *(const float4*)&a[h * Dc + m0 + ty * 4];
        float p0 = 0.4f * (av.x * acc[0][0] + av.y * acc[1][0] + av.z * acc[2][0] + av.w * acc[3][0]);
        float p1 = 0.4f * (av.x * acc[0][1] + av.y * acc[1][1] + av.z * acc[2][1] + av.w * acc[3][1]);
        float p2 = 0.4f * (av.x * acc[0][2] + av.y * acc[1][2] + av.z * acc[2][2] + av.w * acc[3][2]);
        float p3 = 0.4f * (av.x * acc[0][3] + av.y * acc[1][3] + av.z * acc[2][3] + av.w * acc[3][3]);
        p0 += __shfl_xor(p0, 16, 64); p0 += __shfl_xor(p0, 32, 64);
        p1 += __shfl_xor(p1, 16, 64); p1 += __shfl_xor(p1, 32, 64);
        p2 += __shfl_xor(p2, 16, 64); p2 += __shfl_xor(p2, 32, 64);
        p3 += __shfl_xor(p3, 16, 64); p3 += __shfl_xor(p3, 32, 64);
        if (((tid >> 4) & 3) == 0) {
            const int w = tid >> 6;
            red[w][tx][0] = p0; red[w][tx][1] = p1;
            red[w][tx][2] = p2; red[w][tx][3] = p3;
        }
        __syncthreads();
        if (tid < 64) {
            const int txl = tid >> 2, c = tid & 3;
            const float v = red[0][txl][c] + red[1][txl][c] + red[2][txl][c] + red[3][txl][c];
            eb[((h * 4 + b) * 2 + dt) * Kc + n0 + tid] = 1.5f * v;
        }
    }
}

// ---------------------------------------------------------------------------
// K2 (1024 blocks = (hb, 64 i-tiles of 4 rows), 256 thr, XCD-pinned):
//   e-phase: thread (dq=tid>>6, j4=tid&63) owns acc[4i][4j] over a 32-d slice;
//   Rt (bf16) read from global, decoded in-register (lshl/and).
//   Padded-LDS dq-reduce -> wave-per-row shuffle softmax -> write 0.25*P (bf16).
// ---------------------------------------------------------------------------
#define EROW(ACC, LPV)                                            \
    ACC.x = fmaf(aad, __builtin_fabsf((LPV) + rx), ACC.x);        \
    ACC.y = fmaf(aad, __builtin_fabsf((LPV) + ry), ACC.y);        \
    ACC.z = fmaf(aad, __builtin_fabsf((LPV) + rz), ACC.z);        \
    ACC.w = fmaf(aad, __builtin_fabsf((LPV) + rw), ACC.w);

__global__ __launch_bounds__(256) void k2(const float* __restrict__ a,
                                          const float* __restrict__ bias,
                                          const float* __restrict__ Lp,
                                          const unsigned short* __restrict__ Rt,
                                          const float* __restrict__ eb,
                                          unsigned short* __restrict__ Pws) {
    __shared__ float red[256 * 20];   // 20 KB dq-reduce scratch
    __shared__ float lpT[Dc * 4];     // [d][i] 2 KB
    __shared__ float aa[Dc];          // 0.4*a[h]

    const int tid = threadIdx.x;
    const int L = blockIdx.x;
    // XCD-pin: consecutive blockIdx round-robin across XCDs (heuristic).
    const int xcd = L & 7, q = L >> 3;
    const int hb = (xcd << 1) | (q & 1);   // 2 planes per XCD
    const int it = q >> 1;                 // 0..63
    const int h = hb >> 2, b = hb & 3;
    const int i0 = it * 4;

    {
        const int d_s = tid & 127, half = tid >> 7;
        const float* lrow = Lp + (h * Mc + b * Kc + i0 + half * 2) * Dc + d_s;
        lpT[d_s * 4 + half * 2 + 0] = lrow[0];
        lpT[d_s * 4 + half * 2 + 1] = lrow[Dc];
    }
    if (tid < 128) aa[tid] = 0.4f * a[h * Dc + tid];
    __syncthreads();

    const int dq = tid >> 6, j4 = tid & 63;
    float4 acc0 = make_float4(0.f, 0.f, 0.f, 0.f);
    float4 acc1 = make_float4(0.f, 0.f, 0.f, 0.f);
    float4 acc2 = make_float4(0.f, 0.f, 0.f, 0.f);
    float4 acc3 = make_float4(0.f, 0.f, 0.f, 0.f);
    {
        const unsigned short* rb = Rt + (hb * Dc + dq * 32) * Kc + j4 * 4;
        const float* lt = lpT + dq * 32 * 4;
        const float* at = aa + dq * 32;
        #pragma unroll 8
        for (int dd = 0; dd < 32; ++dd) {
            const uint2 rp = *(const uint2*)(rb + dd * Kc);     // 4 bf16, coalesced 512B/row
            const float rx = bf2f_lo(rp.x), ry = bf2f_hi(rp.x);
            const float rz = bf2f_lo(rp.y), rw = bf2f_hi(rp.y);
            const float aad = at[dd];                           // LDS broadcast
            const float4 l0 = *(const float4*)(lt + dd * 4);    // LDS broadcast b128
            EROW(acc0, l0.x); EROW(acc1, l0.y);
            EROW(acc2, l0.z); EROW(acc3, l0.w);
        }
    }
    {
        float* myred = red + tid * 20;
        *(float4*)&myred[0]  = acc0;
        *(float4*)&myred[4]  = acc1;
        *(float4*)&myred[8]  = acc2;
        *(float4*)&myred[12] = acc3;
    }
    __syncthreads();

    // softmax: wave w owns row i0+w; lane l = j-quad
    {
        const int w = tid >> 6, l = tid & 63;
        float4 e0 = make_float4(0.f, 0.f, 0.f, 0.f);
        #pragma unroll
        for (int q4 = 0; q4 < 4; ++q4) {
            const float4 v = *(const float4*)&red[(q4 * 64 + l) * 20 + w * 4];
            e0.x += v.x; e0.y += v.y; e0.z += v.z; e0.w += v.w;
        }
        const float4 eb0 = *(const float4*)&eb[(hb * 2 + 0) * Kc + l * 4];
        const float4 eb1 = *(const float4*)&eb[(hb * 2 + 1) * Kc + l * 4];
        const float4 bv  = *(const float4*)&bias[(h * Kc + i0 + w) * Kc + l * 4];
        e0.x += eb0.x + eb1.x + bv.x;
        e0.y += eb0.y + eb1.y + bv.y;
        e0.z += eb0.z + eb1.z + bv.z;
        e0.w += eb0.w + eb1.w + bv.w;

        float m = fmaxf(fmaxf(e0.x, e0.y), fmaxf(e0.z, e0.w));
        #pragma unroll
        for (int off = 1; off < 64; off <<= 1) m = fmaxf(m, __shfl_xor(m, off, 64));
        const float p0 = __expf(e0.x - m), p1 = __expf(e0.y - m);
        const float p2 = __expf(e0.z - m), p3 = __expf(e0.w - m);
        float s = p0 + p1 + p2 + p3;
        #pragma unroll
        for (int off = 1; off < 64; off <<= 1) s += __shfl_xor(s, off, 64);
        const float sc = 0.25f / s;     // fold mean over H
        uint2 pk;
        pk.x = f2bf(p0 * sc) | (f2bf(p1 * sc) << 16);
        pk.y = f2bf(p2 * sc) | (f2bf(p3 * sc) << 16);
        *(uint2*)&Pws[(hb * Kc + i0 + w) * Kc + l * 4] = pk;
    }
}

// ---------------------------------------------------------------------------
// K3 (512 blocks = (b, 128 i-tiles of 2 rows), 256 thr): P-bar = sum_h Pws(bf16),
// then single PV: out[i][d] = sum_j Pbar[i][j] * x[b][j][d].
// ---------------------------------------------------------------------------
__global__ __launch_bounds__(256) void k3(const float* __restrict__ x,
                                          const unsigned short* __restrict__ Pws,
                                          float* __restrict__ out) {
    __shared__ float pbar[2 * Kc];    // 2 KB
    __shared__ float red[256 * 12];   // 12 KB jq-reduce scratch

    const int tid = threadIdx.x;
    const int bid = blockIdx.x;
    const int b = bid >> 7, it = bid & 127;
    const int i0 = it * 2;

    if (tid < 128) {
        const int r = tid >> 6, c = tid & 63;
        float4 s = make_float4(0.f, 0.f, 0.f, 0.f);
        #pragma unroll
        for (int h = 0; h < 4; ++h) {
            const uint2 v = *(const uint2*)&Pws[((h * 4 + b) * Kc + i0 + r) * Kc + c * 4];
            s.x += bf2f_lo(v.x); s.y += bf2f_hi(v.x);
            s.z += bf2f_lo(v.y); s.w += bf2f_hi(v.y);
        }
        *(float4*)&pbar[r * Kc + c * 4] = s;
    }
    __syncthreads();

    const int jq = tid >> 5, dd4 = tid & 31;
    float4 o0 = make_float4(0.f, 0.f, 0.f, 0.f);
    float4 o1 = make_float4(0.f, 0.f, 0.f, 0.f);
    {
        const float* xb = x + (b * Kc) * Dc + dd4 * 4;
        #pragma unroll 4
        for (int jj = 0; jj < 32; ++jj) {
            const int j = jj * 8 + jq;
            const float4 xv = *(const float4*)(xb + j * Dc);   // global, L2-hot
            const float pv0 = pbar[j];                          // LDS broadcast
            const float pv1 = pbar[Kc + j];
            o0.x = fmaf(pv0, xv.x, o0.x); o0.y = fmaf(pv0, xv.y, o0.y);
            o0.z = fmaf(pv0, xv.z, o0.z); o0.w = fmaf(pv0, xv.w, o0.w);
            o1.x = fmaf(pv1, xv.x, o1.x); o1.y = fmaf(pv1, xv.y, o1.y);
            o1.z = fmaf(pv1, xv.z, o1.z); o1.w = fmaf(pv1, xv.w, o1.w);
        }
    }
    {
        float* myred = red + (jq * 32 + dd4) * 12;
        *(float4*)&myred[0] = o0;
        *(float4*)&myred[4] = o1;
    }
    __syncthreads();
    if (tid < 64) {
        const int i_f = tid >> 5, dd_f = tid & 31;
        float4 s = make_float4(0.f, 0.f, 0.f, 0.f);
        #pragma unroll
        for (int q = 0; q < 8; ++q) {
            const float4 v = *(const float4*)&red[(q * 32 + dd_f) * 12 + i_f * 4];
            s.x += v.x; s.y += v.y; s.z += v.z; s.w += v.w;
        }
        *(float4*)&out[(b * Kc + i0 + i_f) * Dc + dd_f * 4] = s;
    }
}

extern "C" void kernel_launch(void* const* d_in, const int* in_sizes, int n_in,
                              void* d_out, int out_size, void* d_ws, size_t ws_size,
                              hipStream_t stream) {
    const float* x     = (const float*)d_in[0];
    const float* W     = (const float*)d_in[1];
    const float* lin_b = (const float*)d_in[2];
    const float* a     = (const float*)d_in[3];
    const float* bias  = (const float*)d_in[4];
    float* out = (float*)d_out;

    float*          Lp  = (float*)d_ws;                       // fp32 [H][M][D]
    unsigned short* Rt  = (unsigned short*)(Lp + HMD);        // bf16 [(H*B)][D][K]
    float*          eb  = (float*)(Rt + HMD);                 // fp32 [(H*B)][2][K]
    unsigned short* Pws = (unsigned short*)(eb + 8192);       // bf16 [(H*B)][K][K]

    k1<<<256, 256, 0, stream>>>(x, W, lin_b, a, Lp, Rt, eb);
    k2<<<1024, 256, 0, stream>>>(a, bias, Lp, Rt, eb, Pws);
    k3<<<512, 256, 0, stream>>>(x, Pws, out);
}